// Round 2
// baseline (28934.293 us; speedup 1.0000x reference)
//
#include <hip/hip_runtime.h>
#include <cstdio>
#include <cstddef>

#define BB 128
#define SS 512
#define HH 128
#define NG 2048   // 4H * 4 components, permuted column layout n' = m*16 + g*4 + co

typedef unsigned short u16;
typedef __attribute__((ext_vector_type(8))) u16 u16x8;

// Hamilton-product expansion tables: contribution of input component ci to
// output component co uses weight component widx[ci*4+co] with sign sgn[..].
__constant__ int   c_widx[16] = {0,1,2,3, 1,0,3,2, 2,3,0,1, 3,2,1,0};
__constant__ float c_sgn [16] = {1.f,1.f,1.f,1.f, -1.f,1.f,-1.f,1.f,
                                 -1.f,1.f,1.f,-1.f, -1.f,-1.f,1.f,1.f};

__device__ __forceinline__ float fsig(float x) { return 1.f/(1.f + __expf(-x)); }
__device__ __forceinline__ float ftanh(float x) {
  float ax = fabsf(x);
  float e  = __expf(-2.f*ax);
  float tt = (1.f - e)/(1.f + e);
  return copysignf(tt, x);
}
__device__ __forceinline__ float bf2f(u16 u) {
  return __uint_as_float(((unsigned)u) << 16);
}
__device__ __forceinline__ u16 f2bf(float f) {  // round-to-nearest-even
  unsigned u = __float_as_uint(f);
  return (u16)((u + 0x7fffu + ((u >> 16) & 1u)) >> 16);
}

// ---------------- workspace layout ----------------
// fp32 region (element offsets):
constexpr size_t F_W0E  = 0;                              // 512 x 2048
constexpr size_t F_W1E  = F_W0E  + (size_t)512*2048;      // 1024 x 2048
constexpr size_t F_WX0E = F_W1E  + (size_t)1024*2048;     // 4 x 2048
constexpr size_t F_B0P  = F_WX0E + (size_t)4*2048;        // 2048
constexpr size_t F_B1P  = F_B0P  + 2048;                  // 2048
constexpr size_t F_PROJ = F_B1P  + 2048;                  // B*S*128
constexpr size_t F_SCORE= F_PROJ + (size_t)BB*SS*HH;      // B*S
constexpr size_t F_ST   = F_SCORE+ (size_t)BB*SS;         // 6 state bufs B*512 each
constexpr size_t F_END  = F_ST   + (size_t)6*BB*512;
// bf16 region (u16 element offsets, starting at byte F_END*4):
constexpr size_t U_H1   = 0;                              // B*S*512
constexpr size_t U_H2   = U_H1 + (size_t)BB*SS*512;       // B*S*512
constexpr size_t U_END  = U_H2 + (size_t)BB*SS*512;
constexpr size_t NEED_BYTES = F_END*4 + U_END*2;

// ---------------- weight expansion (one launch) ----------------
__global__ __launch_bounds__(256)
void k_expand(const float* __restrict__ Wh0, const float* __restrict__ Wx1,
              const float* __restrict__ Wh1, const float* __restrict__ Wx0,
              const float* __restrict__ b0,  const float* __restrict__ b1,
              float* __restrict__ ws)
{
  const size_t idx = (size_t)blockIdx.x*256 + threadIdx.x;
  if (idx >= (size_t)1024*NG) return;
  const int k  = (int)(idx / NG);
  const int np = (int)(idx % NG);
  const int ci = k & 3;
  const int m  = np >> 4;
  const int g  = (np >> 2) & 3;
  const int co = np & 3;
  const int o  = g*HH + m;
  const int wi = c_widx[ci*4+co];
  const float sg = c_sgn[ci*4+co];

  { // W1e: rows 0..511 from Wx1 (x-proj folded into step), 512..1023 from Wh1
    const float* srcW = (k < 512) ? Wx1 : Wh1;
    const int km = (k < 512) ? (k >> 2) : ((k - 512) >> 2);
    ws[F_W1E + idx] = sg * srcW[((size_t)wi << 16) + ((size_t)km << 9) + o];
  }
  if (idx < (size_t)512*NG) { // W0e (recurrent weights layer 0)
    ws[F_W0E + idx] = sg * Wh0[((size_t)wi << 16) + ((size_t)(k >> 2) << 9) + o];
  }
  if (idx < (size_t)4*NG) {   // Wx0e: layer-0 input projection (in=1); ci == k
    ws[F_WX0E + idx] = sg * Wx0[(size_t)wi*512 + o];
  }
  if (idx < (size_t)NG) {     // permuted biases
    ws[F_B0P + idx] = b0[(size_t)o*4 + co];
    ws[F_B1P + idx] = b1[(size_t)o*4 + co];
  }
}

__global__ __launch_bounds__(256)
void k_init(float* __restrict__ p)
{
  const size_t i = (size_t)blockIdx.x*256 + threadIdx.x;
  if (i < (size_t)6*BB*512) p[i] = 0.f;
}

// ---------------- fused LSTM step (gates GEMM + cell update) ----------------
// grid: (64 col-tiles of 32, 4 batch-tiles of 32); block 256.
// NSTAGE=1: layer 0 (K=512, x-projection on the fly via Wx0e), xin = x fp32
// NSTAGE=2: layer 1 (K=1024 = [h1_t | h_prev], Wx1 folded), xin = h1 bf16
template<int NSTAGE>
__global__ __launch_bounds__(256)
void k_step(const float* __restrict__ W, const float* __restrict__ bias,
            const void* __restrict__ xin_v, const float* __restrict__ wx0e,
            const float* __restrict__ hprev, float* __restrict__ hnext,
            float* __restrict__ cst, u16* __restrict__ hout, int t)
{
  __shared__ float hs[32][260];   // K-chunk of input rows
  __shared__ float gs[32][33];    // gates tile for cell phase
  const int tid = threadIdx.x;
  const int nt  = blockIdx.x;     // 0..63 -> 32 cols = 2 h-indices
  const int bt  = blockIdx.y;     // 0..3  -> 32 batch rows
  const int b0r = bt*32;
  const int n0c = nt*32;
  const int rr  = tid >> 3;       // row in tile 0..31
  const int jg  = tid & 7;        // col group (4 cols)
  const int n   = n0c + jg*4;

  float4 acc = *(const float4*)&bias[n];
  if constexpr (NSTAGE == 1) {
    const float* x = (const float*)xin_v;
    const float* xr = &x[((size_t)(b0r + rr)*SS + (size_t)t)*4];
    const float x0 = xr[0], x1 = xr[1], x2 = xr[2], x3 = xr[3];
    const float4 w0 = *(const float4*)&wx0e[0*NG + n];
    const float4 w1 = *(const float4*)&wx0e[1*NG + n];
    const float4 w2 = *(const float4*)&wx0e[2*NG + n];
    const float4 w3 = *(const float4*)&wx0e[3*NG + n];
    acc.x += x0*w0.x + x1*w1.x + x2*w2.x + x3*w3.x;
    acc.y += x0*w0.y + x1*w1.y + x2*w2.y + x3*w3.y;
    acc.z += x0*w0.z + x1*w1.z + x2*w2.z + x3*w3.z;
    acc.w += x0*w0.w + x1*w1.w + x2*w2.w + x3*w3.w;
  }

  const int KTOT = NSTAGE*512;
  for (int q = 0; q < KTOT/256; ++q) {
    const int kglob = q*256;
    __syncthreads();
    if (NSTAGE == 2 && kglob < 512) {       // bf16 h1 sequence input
      const u16* h1 = (const u16*)xin_v;
      const u16* src = h1 + ((size_t)b0r*SS + (size_t)t)*512 + kglob;
      const size_t rs = (size_t)SS*512;
      for (int f = tid*8; f < 32*256; f += 2048) {
        const int lr = f >> 8, lc = f & 255;
        u16x8 rv = *(const u16x8*)&src[(size_t)lr*rs + lc];
        float4 a, b;
        a.x=bf2f(rv[0]); a.y=bf2f(rv[1]); a.z=bf2f(rv[2]); a.w=bf2f(rv[3]);
        b.x=bf2f(rv[4]); b.y=bf2f(rv[5]); b.z=bf2f(rv[6]); b.w=bf2f(rv[7]);
        *(float4*)&hs[lr][lc]   = a;
        *(float4*)&hs[lr][lc+4] = b;
      }
    } else {                                 // fp32 recurrent state
      const int coff = kglob - (NSTAGE == 2 ? 512 : 0);
      const float* src = hprev + (size_t)b0r*512 + coff;
      for (int f = tid*4; f < 32*256; f += 1024) {
        const int lr = f >> 8, lc = f & 255;
        *(float4*)&hs[lr][lc] = *(const float4*)&src[(size_t)lr*512 + lc];
      }
    }
    __syncthreads();
    const float* Wb = W + (size_t)kglob*NG + n;
    #pragma unroll 2
    for (int kk = 0; kk < 256; kk += 4) {
      const float4 hv = *(const float4*)&hs[rr][kk];
      const float* wp = Wb + (size_t)kk*NG;
      const float4 w0 = *(const float4*)(wp);
      const float4 w1 = *(const float4*)(wp + NG);
      const float4 w2 = *(const float4*)(wp + 2*NG);
      const float4 w3 = *(const float4*)(wp + 3*NG);
      acc.x += hv.x*w0.x + hv.y*w1.x + hv.z*w2.x + hv.w*w3.x;
      acc.y += hv.x*w0.y + hv.y*w1.y + hv.z*w2.y + hv.w*w3.y;
      acc.z += hv.x*w0.z + hv.y*w1.z + hv.z*w2.z + hv.w*w3.z;
      acc.w += hv.x*w0.w + hv.y*w1.w + hv.z*w2.w + hv.w*w3.w;
    }
  }
  gs[rr][jg*4+0] = acc.x;
  gs[rr][jg*4+1] = acc.y;
  gs[rr][jg*4+2] = acc.z;
  gs[rr][jg*4+3] = acc.w;
  __syncthreads();
  { // cell update: thread -> (row, m_local, component)
    const int cr = tid >> 3;
    const int ml = (tid >> 2) & 1;
    const int co = tid & 3;
    const float ig = fsig (gs[cr][ml*16 + 0  + co]);
    const float fg = fsig (gs[cr][ml*16 + 4  + co]);
    const float gg = ftanh(gs[cr][ml*16 + 8  + co]);
    const float og = fsig (gs[cr][ml*16 + 12 + co]);
    const int b = b0r + cr;
    const int m = nt*2 + ml;
    const size_t cidx = (size_t)b*512 + (size_t)m*4 + co;
    const float cn = fg*cst[cidx] + ig*gg;
    const float hn = og*ftanh(cn);
    cst[cidx] = cn;
    hnext[cidx] = hn;
    hout[((size_t)b*SS + (size_t)t)*512 + (size_t)m*4 + co] = f2bf(hn);
  }
}

// ---------------- head: projected = h2flat @ Wp + bp ----------------
__global__ __launch_bounds__(256)
void k_proj(const u16* __restrict__ h2, const float* __restrict__ Wp,
            const float* __restrict__ bp, float* __restrict__ proj)
{
  __shared__ float hsh[8][512];
  const int tid = threadIdx.x;
  const int j   = tid & 127;
  const int rh  = tid >> 7;
  const size_t bs0 = (size_t)blockIdx.x * 8;
  for (int f = tid*8; f < 8*512; f += 2048) {
    const int lr = f >> 9, lc = f & 511;
    u16x8 rv = *(const u16x8*)&h2[(bs0 + lr)*512 + lc];
    float4 a, b;
    a.x=bf2f(rv[0]); a.y=bf2f(rv[1]); a.z=bf2f(rv[2]); a.w=bf2f(rv[3]);
    b.x=bf2f(rv[4]); b.y=bf2f(rv[5]); b.z=bf2f(rv[6]); b.w=bf2f(rv[7]);
    *(float4*)&hsh[lr][lc]   = a;
    *(float4*)&hsh[lr][lc+4] = b;
  }
  __syncthreads();
  const float bv = bp[j];
  float a0=bv, a1=bv, a2=bv, a3=bv;
  #pragma unroll 2
  for (int kk = 0; kk < 512; kk += 4) {
    const float w0 = Wp[(size_t)(kk+0)*HH + j];
    const float w1 = Wp[(size_t)(kk+1)*HH + j];
    const float w2 = Wp[(size_t)(kk+2)*HH + j];
    const float w3 = Wp[(size_t)(kk+3)*HH + j];
    const float4 h0 = *(const float4*)&hsh[rh*4+0][kk];
    const float4 h1 = *(const float4*)&hsh[rh*4+1][kk];
    const float4 h2v= *(const float4*)&hsh[rh*4+2][kk];
    const float4 h3 = *(const float4*)&hsh[rh*4+3][kk];
    a0 += h0.x*w0  + h0.y*w1  + h0.z*w2  + h0.w*w3;
    a1 += h1.x*w0  + h1.y*w1  + h1.z*w2  + h1.w*w3;
    a2 += h2v.x*w0 + h2v.y*w1 + h2v.z*w2 + h2v.w*w3;
    a3 += h3.x*w0  + h3.y*w1  + h3.z*w2  + h3.w*w3;
  }
  proj[(bs0 + rh*4+0)*HH + j] = a0;
  proj[(bs0 + rh*4+1)*HH + j] = a1;
  proj[(bs0 + rh*4+2)*HH + j] = a2;
  proj[(bs0 + rh*4+3)*HH + j] = a3;
}

// ---------------- head: scores = tanh(proj @ Wa + ba) @ va ----------------
__global__ __launch_bounds__(256)
void k_scores(const float* __restrict__ proj, const float* __restrict__ Wa,
              const float* __restrict__ ba, const float* __restrict__ va,
              float* __restrict__ scores)
{
  __shared__ float was[64*128];   // one K-half of Wa
  __shared__ float ps[32][128];
  __shared__ float red[4];
  const int tid = threadIdx.x;
  const size_t bs0 = (size_t)blockIdx.x * 32;
  for (int f = tid*4; f < 32*128; f += 1024) {
    const int lr = f >> 7, lc = f & 127;
    *(float4*)&ps[lr][lc] = *(const float4*)&proj[(bs0 + lr)*HH + lc];
  }
  const int j  = tid & 127;
  const int rh = tid >> 7;
  float yacc[16];
  const float bav = ba[j];
  #pragma unroll
  for (int rp = 0; rp < 16; ++rp) yacc[rp] = bav;
  for (int half = 0; half < 2; ++half) {
    __syncthreads();
    for (int f = tid*4; f < 64*128; f += 1024)
      *(float4*)&was[f] = *(const float4*)&Wa[(size_t)half*8192 + f];
    __syncthreads();
    for (int rp = 0; rp < 16; ++rp) {
      const int row = rp*2 + rh;
      float y = yacc[rp];
      #pragma unroll 8
      for (int i2 = 0; i2 < 64; ++i2)
        y += ps[row][half*64 + i2] * was[i2*128 + j];
      yacc[rp] = y;
    }
  }
  const float vav = va[j];
  for (int rp = 0; rp < 16; ++rp) {
    float y = ftanh(yacc[rp]) * vav;
    for (int off = 32; off > 0; off >>= 1) y += __shfl_down(y, off);
    __syncthreads();
    if ((tid & 63) == 0) red[tid >> 6] = y;
    __syncthreads();
    if (tid == 0) scores[bs0 + rp*2 + 0] = red[0] + red[1];
    if (tid == 1) scores[bs0 + rp*2 + 1] = red[2] + red[3];
  }
}

// ---------------- head: softmax + context + output ----------------
__global__ __launch_bounds__(256)
void k_final(const float* __restrict__ proj, const float* __restrict__ scores,
             const float* __restrict__ Wo, const float* __restrict__ bo,
             float* __restrict__ out)
{
  __shared__ float sc[512];
  __shared__ float red[4];
  __shared__ float ctx2[2][128];
  const int tid = threadIdx.x;
  const int b = blockIdx.x;
  *(float2*)&sc[tid*2] = *(const float2*)&scores[(size_t)b*SS + tid*2];
  __syncthreads();
  float m = fmaxf(sc[tid], sc[tid+256]);
  for (int off = 32; off > 0; off >>= 1) m = fmaxf(m, __shfl_down(m, off));
  if ((tid & 63) == 0) red[tid >> 6] = m;
  __syncthreads();
  const float M = fmaxf(fmaxf(red[0], red[1]), fmaxf(red[2], red[3]));
  __syncthreads();
  const float e0 = __expf(sc[tid]     - M);
  const float e1 = __expf(sc[tid+256] - M);
  sc[tid] = e0; sc[tid+256] = e1;
  float s = e0 + e1;
  for (int off = 32; off > 0; off >>= 1) s += __shfl_down(s, off);
  if ((tid & 63) == 0) red[tid >> 6] = s;
  __syncthreads();
  const float rinv = 1.f/(red[0] + red[1] + red[2] + red[3]);
  const int h  = tid & 127;
  const int sh = tid >> 7;
  float cp = 0.f;
  #pragma unroll 4
  for (int ssi = sh*256; ssi < sh*256 + 256; ++ssi)
    cp += sc[ssi]*proj[((size_t)b*SS + ssi)*HH + h];
  ctx2[sh][h] = cp;
  __syncthreads();
  if (tid < 128) {
    const float ctx = (ctx2[0][tid] + ctx2[1][tid])*rinv;
    float v = ctx*Wo[tid];
    for (int off = 32; off > 0; off >>= 1) v += __shfl_down(v, off);
    if ((tid & 63) == 0) red[tid >> 6] = v;
  }
  __syncthreads();
  if (tid == 0) out[b] = red[0] + red[1] + bo[0];
}

// ---------------- host ----------------
extern "C" void kernel_launch(void* const* d_in, const int* in_sizes, int n_in,
                              void* d_out, int out_size, void* d_ws, size_t ws_size,
                              hipStream_t stream)
{
  (void)in_sizes; (void)n_in;
  const float* x   = (const float*)d_in[0];
  const float* Wx0 = (const float*)d_in[1];
  const float* Wh0 = (const float*)d_in[2];
  const float* b0  = (const float*)d_in[3];
  const float* Wx1 = (const float*)d_in[4];
  const float* Wh1 = (const float*)d_in[5];
  const float* b1  = (const float*)d_in[6];
  const float* Wp  = (const float*)d_in[7];
  const float* bp  = (const float*)d_in[8];
  const float* Wa  = (const float*)d_in[9];
  const float* ba  = (const float*)d_in[10];
  const float* va  = (const float*)d_in[11];
  const float* Wo  = (const float*)d_in[12];
  const float* bo  = (const float*)d_in[13];
  float* ws = (float*)d_ws;
  u16*   wsu = (u16*)((char*)d_ws + F_END*4);

  if (ws_size < NEED_BYTES) {
    fprintf(stderr, "[qnn] ws too small: have=%zu need=%zu\n", ws_size, NEED_BYTES);
    return;
  }

  k_expand<<<8192, 256, 0, stream>>>(Wh0, Wx1, Wh1, Wx0, b0, b1, ws);
  k_init  <<<1536, 256, 0, stream>>>(ws + F_ST);

  u16* h1buf = wsu + U_H1;
  u16* h2buf = wsu + U_H2;
  float* H0A = ws + F_ST;
  float* H0B = H0A + (size_t)BB*512;
  float* C0  = H0B + (size_t)BB*512;
  float* H1A = C0  + (size_t)BB*512;
  float* H1B = H1A + (size_t)BB*512;
  float* C1  = H1B + (size_t)BB*512;

  for (int t = 0; t < SS; ++t) {
    const float* hp = (t & 1) ? H0B : H0A;
    float*       hn = (t & 1) ? H0A : H0B;
    k_step<1><<<dim3(64,4), 256, 0, stream>>>(ws + F_W0E, ws + F_B0P, x,
                                              ws + F_WX0E, hp, hn,
                                              C0, h1buf, t);
  }
  for (int t = 0; t < SS; ++t) {
    const float* hp = (t & 1) ? H1B : H1A;
    float*       hn = (t & 1) ? H1A : H1B;
    k_step<2><<<dim3(64,4), 256, 0, stream>>>(ws + F_W1E, ws + F_B1P, h1buf,
                                              nullptr, hp, hn,
                                              C1, h2buf, t);
  }
  k_proj  <<<BB*SS/8,  256, 0, stream>>>(h2buf, Wp, bp, ws + F_PROJ);
  k_scores<<<BB*SS/32, 256, 0, stream>>>(ws + F_PROJ, Wa, ba, va, ws + F_SCORE);
  k_final <<<BB,       256, 0, stream>>>(ws + F_PROJ, ws + F_SCORE, Wo, bo,
                                         (float*)d_out);
}

// Round 3
// 6596.396 us; speedup vs baseline: 4.3864x; 4.3864x over previous
//
#include <hip/hip_runtime.h>
#include <cstdio>
#include <cstddef>

#define BB 128
#define SS 512
#define HH 128
#define NG 2048   // 4H*4 components, permuted column layout n' = m*16 + g*4 + co

typedef unsigned short u16;
typedef __attribute__((ext_vector_type(8))) u16   u16x8;
typedef __attribute__((ext_vector_type(8))) short s16x8;
typedef __attribute__((ext_vector_type(4))) float f32x4;

// Hamilton-product expansion tables: contribution of input component ci to
// output component co uses weight component widx[ci*4+co] with sign sgn[..].
__constant__ int   c_widx[16] = {0,1,2,3, 1,0,3,2, 2,3,0,1, 3,2,1,0};
__constant__ float c_sgn [16] = {1.f,1.f,1.f,1.f, -1.f,1.f,-1.f,1.f,
                                 -1.f,1.f,1.f,-1.f, -1.f,-1.f,1.f,1.f};

__device__ __forceinline__ float fsig(float x) { return 1.f/(1.f + __expf(-x)); }
__device__ __forceinline__ float ftanh(float x) {
  float ax = fabsf(x);
  float e  = __expf(-2.f*ax);
  float tt = (1.f - e)/(1.f + e);
  return copysignf(tt, x);
}
__device__ __forceinline__ float bf2f(u16 u) {
  return __uint_as_float(((unsigned)u) << 16);
}
__device__ __forceinline__ u16 f2bf(float f) {  // round-to-nearest-even
  unsigned u = __float_as_uint(f);
  return (u16)((u + 0x7fffu + ((u >> 16) & 1u)) >> 16);
}

// ---------------- workspace layout ----------------
// fp32 region (element offsets):
constexpr size_t F_B0P  = 0;                               // 2048
constexpr size_t F_B1P  = F_B0P  + 2048;                   // 2048
constexpr size_t F_WX0E = F_B1P  + 2048;                   // 4*2048
constexpr size_t F_PROJ = F_WX0E + 8192;                   // B*S*128
constexpr size_t F_SCORE= F_PROJ + (size_t)BB*SS*HH;       // B*S
constexpr size_t F_C0   = F_SCORE+ (size_t)BB*SS;          // B*512
constexpr size_t F_C1   = F_C0   + (size_t)BB*512;         // B*512
constexpr size_t F_END  = F_C1   + (size_t)BB*512;
// u16 (bf16) region, starts at byte F_END*4 (16B aligned):
constexpr size_t U_WB0  = 0;                               // 128*16*64*8
constexpr size_t U_WB1  = U_WB0 + (size_t)128*16*64*8;     // 128*32*64*8
constexpr size_t U_H1   = U_WB1 + (size_t)128*32*64*8;     // B*S*512
constexpr size_t U_H2   = U_H1  + (size_t)BB*SS*512;       // B*S*512
constexpr size_t U_H0A  = U_H2  + (size_t)BB*SS*512;       // B*512 x4 state
constexpr size_t U_H0B  = U_H0A + (size_t)BB*512;
constexpr size_t U_H1A  = U_H0B + (size_t)BB*512;
constexpr size_t U_H1B  = U_H1A + (size_t)BB*512;
constexpr size_t U_END  = U_H1B + (size_t)BB*512;
constexpr size_t NEED_BYTES = F_END*4 + U_END*2;

// ---------------- weight expansion into bf16 fragment-major ----------------
// WB[nt][ks][lane][e]: element W[k = ks*32 + (lane>>4)*8 + e][n' = nt*16 + (lane&15)]
// One thread per WB1 element (2M); smaller jobs piggyback on low idx.
__global__ __launch_bounds__(256)
void k_expand(const float* __restrict__ Wh0, const float* __restrict__ Wx1,
              const float* __restrict__ Wh1, const float* __restrict__ Wx0,
              const float* __restrict__ b0,  const float* __restrict__ b1,
              u16* __restrict__ WB0, u16* __restrict__ WB1,
              float* __restrict__ wx0e, float* __restrict__ b0p,
              float* __restrict__ b1p)
{
  const int idx = blockIdx.x*256 + threadIdx.x;   // 0 .. 2M-1 exactly
  { // WB1 (layer 1, K=1024: rows 0..511 = Wx1 on h1_t, 512..1023 = Wh1)
    const int e  = idx & 7;
    const int ln = (idx >> 3) & 63;
    const int ks = (idx >> 9) & 31;
    const int nt = idx >> 14;
    const int k  = ks*32 + (ln >> 4)*8 + e;
    const int np = nt*16 + (ln & 15);
    const int g  = (np >> 2) & 3, co = np & 3;
    const int o  = g*HH + nt;
    const int ci = k & 3;
    const int wi = c_widx[ci*4+co];
    const float sg = c_sgn[ci*4+co];
    const float wv = (k < 512)
      ? Wx1[((size_t)wi*HH + (k >> 2))*512 + o]
      : Wh1[((size_t)wi*HH + ((k - 512) >> 2))*512 + o];
    WB1[idx] = f2bf(sg*wv);
  }
  if (idx < 128*16*64*8) { // WB0 (layer 0 recurrent, K=512)
    const int e  = idx & 7;
    const int ln = (idx >> 3) & 63;
    const int ks = (idx >> 9) & 15;
    const int nt = idx >> 13;
    const int k  = ks*32 + (ln >> 4)*8 + e;
    const int np = nt*16 + (ln & 15);
    const int g  = (np >> 2) & 3, co = np & 3;
    const int o  = g*HH + nt;
    const int ci = k & 3;
    const int wi = c_widx[ci*4+co];
    const float sg = c_sgn[ci*4+co];
    WB0[idx] = f2bf(sg*Wh0[((size_t)wi*HH + (k >> 2))*512 + o]);
  }
  if (idx < 8192) { // wx0e[ci][n'] fp32 (layer-0 input proj, in=1)
    const int ci = idx >> 11, np = idx & 2047;
    const int m = np >> 4, g = (np >> 2) & 3, co = np & 3;
    const int o = g*HH + m;
    wx0e[idx] = c_sgn[ci*4+co]*Wx0[(size_t)c_widx[ci*4+co]*512 + o];
  }
  if (idx < 2048) { // permuted biases fp32
    const int np = idx;
    const int m = np >> 4, g = (np >> 2) & 3, co = np & 3;
    const int o = g*HH + m;
    b0p[idx] = b0[(size_t)o*4 + co];
    b1p[idx] = b1[(size_t)o*4 + co];
  }
}

__global__ __launch_bounds__(256)
void k_init(float* __restrict__ cz, u16* __restrict__ hz)
{
  const int i = blockIdx.x*256 + threadIdx.x;   // 32768 threads
  ((float4*)cz)[i] = make_float4(0.f,0.f,0.f,0.f);
  ((uint4*)hz)[i]  = make_uint4(0u,0u,0u,0u);
}

// ---------------- MFMA fused LSTM step ----------------
// grid (64,4), block 256 = 4 waves in 2x2: wave w -> rows (by*32 + (w>>1)*16),
// ntile (bx*2 + (w&1)). Each wave: 16 batch rows x 1 h-index (16 gate cols),
// K = NSTAGE*512 via 16*NSTAGE mfma_f32_16x16x32_bf16, then cell update.
template<int NSTAGE>
__global__ __launch_bounds__(256)
void k_step(const u16* __restrict__ WB, const float* __restrict__ bias,
            const void* __restrict__ xin_v, const float* __restrict__ wx0e,
            const u16* __restrict__ hprev, u16* __restrict__ hnext,
            float* __restrict__ cst, u16* __restrict__ hseq, int t)
{
  __shared__ float gs[4][16][17];
  const int tid  = threadIdx.x;
  const int w    = tid >> 6;
  const int l    = tid & 63;
  const int nt   = blockIdx.x*2 + (w & 1);        // h index m, 0..127
  const int r0   = blockIdx.y*32 + (w >> 1)*16;   // batch row base
  const int lrow = l & 15;
  const int lg   = l >> 4;

  f32x4 acc = {0.f, 0.f, 0.f, 0.f};
  const int KS = NSTAGE*16;
  const u16* wb = WB + ((size_t)nt*KS*64 + (size_t)l)*8;

  if constexpr (NSTAGE == 1) {
    const u16* ap = hprev + (size_t)(r0 + lrow)*512 + lg*8;
    #pragma unroll
    for (int ks = 0; ks < 16; ++ks) {
      s16x8 a = *(const s16x8*)(ap + ks*32);
      s16x8 b = *(const s16x8*)(wb + (size_t)ks*512);
      acc = __builtin_amdgcn_mfma_f32_16x16x32_bf16(a, b, acc, 0, 0, 0);
    }
  } else {
    const u16* h1  = (const u16*)xin_v;
    const u16* ap1 = h1 + ((size_t)(r0 + lrow)*SS + (size_t)t)*512 + lg*8;
    const u16* ap2 = hprev + (size_t)(r0 + lrow)*512 + lg*8;
    #pragma unroll
    for (int ks = 0; ks < 16; ++ks) {
      s16x8 a = *(const s16x8*)(ap1 + ks*32);
      s16x8 b = *(const s16x8*)(wb + (size_t)ks*512);
      acc = __builtin_amdgcn_mfma_f32_16x16x32_bf16(a, b, acc, 0, 0, 0);
    }
    #pragma unroll
    for (int ks = 0; ks < 16; ++ks) {
      s16x8 a = *(const s16x8*)(ap2 + ks*32);
      s16x8 b = *(const s16x8*)(wb + (size_t)(16 + ks)*512);
      acc = __builtin_amdgcn_mfma_f32_16x16x32_bf16(a, b, acc, 0, 0, 0);
    }
  }

  // epilogue: bias (+ x-term for layer 0), transpose via LDS, cell update
  const float bv = bias[nt*16 + lrow];
  if constexpr (NSTAGE == 1) {
    const float* x = (const float*)xin_v;
    #pragma unroll
    for (int r = 0; r < 4; ++r) {
      const int brow = r0 + lg*4 + r;
      const float4 xv = *(const float4*)&x[((size_t)brow*SS + (size_t)t)*4];
      float v = acc[r] + bv
        + xv.x*wx0e[0*NG + nt*16 + lrow] + xv.y*wx0e[1*NG + nt*16 + lrow]
        + xv.z*wx0e[2*NG + nt*16 + lrow] + xv.w*wx0e[3*NG + nt*16 + lrow];
      gs[w][lg*4 + r][lrow] = v;
    }
  } else {
    #pragma unroll
    for (int r = 0; r < 4; ++r)
      gs[w][lg*4 + r][lrow] = acc[r] + bv;
  }
  __syncthreads();
  { // lane -> (local row = l>>2, component co = l&3); cols g*4+co hold gates
    const int row = l >> 2, co = l & 3;
    const float i_g = fsig (gs[w][row][0*4 + co]);
    const float f_g = fsig (gs[w][row][1*4 + co]);
    const float g_g = ftanh(gs[w][row][2*4 + co]);
    const float o_g = fsig (gs[w][row][3*4 + co]);
    const int b = r0 + row;
    const size_t cidx = (size_t)b*512 + (size_t)nt*4 + co;
    const float cn = f_g*cst[cidx] + i_g*g_g;
    const float hn = o_g*ftanh(cn);
    cst[cidx] = cn;
    const u16 hb = f2bf(hn);
    hnext[cidx] = hb;
    hseq[((size_t)b*SS + (size_t)t)*512 + (size_t)nt*4 + co] = hb;
  }
}

// ---------------- head: projected = h2flat @ Wp + bp ----------------
__global__ __launch_bounds__(256)
void k_proj(const u16* __restrict__ h2, const float* __restrict__ Wp,
            const float* __restrict__ bp, float* __restrict__ proj)
{
  __shared__ float hsh[8][512];
  const int tid = threadIdx.x;
  const int j   = tid & 127;
  const int rh  = tid >> 7;
  const size_t bs0 = (size_t)blockIdx.x * 8;
  for (int f = tid*8; f < 8*512; f += 2048) {
    const int lr = f >> 9, lc = f & 511;
    u16x8 rv = *(const u16x8*)&h2[(bs0 + lr)*512 + lc];
    float4 a, b;
    a.x=bf2f(rv[0]); a.y=bf2f(rv[1]); a.z=bf2f(rv[2]); a.w=bf2f(rv[3]);
    b.x=bf2f(rv[4]); b.y=bf2f(rv[5]); b.z=bf2f(rv[6]); b.w=bf2f(rv[7]);
    *(float4*)&hsh[lr][lc]   = a;
    *(float4*)&hsh[lr][lc+4] = b;
  }
  __syncthreads();
  const float bv = bp[j];
  float a0=bv, a1=bv, a2=bv, a3=bv;
  #pragma unroll 2
  for (int kk = 0; kk < 512; kk += 4) {
    const float w0 = Wp[(size_t)(kk+0)*HH + j];
    const float w1 = Wp[(size_t)(kk+1)*HH + j];
    const float w2 = Wp[(size_t)(kk+2)*HH + j];
    const float w3 = Wp[(size_t)(kk+3)*HH + j];
    const float4 h0 = *(const float4*)&hsh[rh*4+0][kk];
    const float4 h1 = *(const float4*)&hsh[rh*4+1][kk];
    const float4 h2v= *(const float4*)&hsh[rh*4+2][kk];
    const float4 h3 = *(const float4*)&hsh[rh*4+3][kk];
    a0 += h0.x*w0  + h0.y*w1  + h0.z*w2  + h0.w*w3;
    a1 += h1.x*w0  + h1.y*w1  + h1.z*w2  + h1.w*w3;
    a2 += h2v.x*w0 + h2v.y*w1 + h2v.z*w2 + h2v.w*w3;
    a3 += h3.x*w0  + h3.y*w1  + h3.z*w2  + h3.w*w3;
  }
  proj[(bs0 + rh*4+0)*HH + j] = a0;
  proj[(bs0 + rh*4+1)*HH + j] = a1;
  proj[(bs0 + rh*4+2)*HH + j] = a2;
  proj[(bs0 + rh*4+3)*HH + j] = a3;
}

// ---------------- head: scores = tanh(proj @ Wa + ba) @ va ----------------
__global__ __launch_bounds__(256)
void k_scores(const float* __restrict__ proj, const float* __restrict__ Wa,
              const float* __restrict__ ba, const float* __restrict__ va,
              float* __restrict__ scores)
{
  __shared__ float was[64*128];
  __shared__ float ps[32][128];
  __shared__ float red[4];
  const int tid = threadIdx.x;
  const size_t bs0 = (size_t)blockIdx.x * 32;
  for (int f = tid*4; f < 32*128; f += 1024) {
    const int lr = f >> 7, lc = f & 127;
    *(float4*)&ps[lr][lc] = *(const float4*)&proj[(bs0 + lr)*HH + lc];
  }
  const int j  = tid & 127;
  const int rh = tid >> 7;
  float yacc[16];
  const float bav = ba[j];
  #pragma unroll
  for (int rp = 0; rp < 16; ++rp) yacc[rp] = bav;
  for (int half = 0; half < 2; ++half) {
    __syncthreads();
    for (int f = tid*4; f < 64*128; f += 1024)
      *(float4*)&was[f] = *(const float4*)&Wa[(size_t)half*8192 + f];
    __syncthreads();
    for (int rp = 0; rp < 16; ++rp) {
      const int row = rp*2 + rh;
      float y = yacc[rp];
      #pragma unroll 8
      for (int i2 = 0; i2 < 64; ++i2)
        y += ps[row][half*64 + i2] * was[i2*128 + j];
      yacc[rp] = y;
    }
  }
  const float vav = va[j];
  for (int rp = 0; rp < 16; ++rp) {
    float y = ftanh(yacc[rp]) * vav;
    for (int off = 32; off > 0; off >>= 1) y += __shfl_down(y, off);
    __syncthreads();
    if ((tid & 63) == 0) red[tid >> 6] = y;
    __syncthreads();
    if (tid == 0) scores[bs0 + rp*2 + 0] = red[0] + red[1];
    if (tid == 1) scores[bs0 + rp*2 + 1] = red[2] + red[3];
  }
}

// ---------------- head: softmax + context + output ----------------
__global__ __launch_bounds__(256)
void k_final(const float* __restrict__ proj, const float* __restrict__ scores,
             const float* __restrict__ Wo, const float* __restrict__ bo,
             float* __restrict__ out)
{
  __shared__ float sc[512];
  __shared__ float red[4];
  __shared__ float ctx2[2][128];
  const int tid = threadIdx.x;
  const int b = blockIdx.x;
  *(float2*)&sc[tid*2] = *(const float2*)&scores[(size_t)b*SS + tid*2];
  __syncthreads();
  float m = fmaxf(sc[tid], sc[tid+256]);
  for (int off = 32; off > 0; off >>= 1) m = fmaxf(m, __shfl_down(m, off));
  if ((tid & 63) == 0) red[tid >> 6] = m;
  __syncthreads();
  const float M = fmaxf(fmaxf(red[0], red[1]), fmaxf(red[2], red[3]));
  __syncthreads();
  const float e0 = __expf(sc[tid]     - M);
  const float e1 = __expf(sc[tid+256] - M);
  sc[tid] = e0; sc[tid+256] = e1;
  float s = e0 + e1;
  for (int off = 32; off > 0; off >>= 1) s += __shfl_down(s, off);
  if ((tid & 63) == 0) red[tid >> 6] = s;
  __syncthreads();
  const float rinv = 1.f/(red[0] + red[1] + red[2] + red[3]);
  const int h  = tid & 127;
  const int sh = tid >> 7;
  float cp = 0.f;
  #pragma unroll 4
  for (int ssi = sh*256; ssi < sh*256 + 256; ++ssi)
    cp += sc[ssi]*proj[((size_t)b*SS + ssi)*HH + h];
  ctx2[sh][h] = cp;
  __syncthreads();
  if (tid < 128) {
    const float ctx = (ctx2[0][tid] + ctx2[1][tid])*rinv;
    float v = ctx*Wo[tid];
    for (int off = 32; off > 0; off >>= 1) v += __shfl_down(v, off);
    if ((tid & 63) == 0) red[tid >> 6] = v;
  }
  __syncthreads();
  if (tid == 0) out[b] = red[0] + red[1] + bo[0];
}

// ---------------- host ----------------
extern "C" void kernel_launch(void* const* d_in, const int* in_sizes, int n_in,
                              void* d_out, int out_size, void* d_ws, size_t ws_size,
                              hipStream_t stream)
{
  (void)in_sizes; (void)n_in; (void)out_size;
  const float* x   = (const float*)d_in[0];
  const float* Wx0 = (const float*)d_in[1];
  const float* Wh0 = (const float*)d_in[2];
  const float* b0  = (const float*)d_in[3];
  const float* Wx1 = (const float*)d_in[4];
  const float* Wh1 = (const float*)d_in[5];
  const float* b1  = (const float*)d_in[6];
  const float* Wp  = (const float*)d_in[7];
  const float* bp  = (const float*)d_in[8];
  const float* Wa  = (const float*)d_in[9];
  const float* ba  = (const float*)d_in[10];
  const float* va  = (const float*)d_in[11];
  const float* Wo  = (const float*)d_in[12];
  const float* bo  = (const float*)d_in[13];
  float* ws  = (float*)d_ws;
  u16*   wsu = (u16*)((char*)d_ws + F_END*4);

  if (ws_size < NEED_BYTES) {
    fprintf(stderr, "[qnn] ws too small: have=%zu need=%zu\n", ws_size, NEED_BYTES);
    return;
  }

  k_expand<<<8192, 256, 0, stream>>>(Wh0, Wx1, Wh1, Wx0, b0, b1,
                                     wsu + U_WB0, wsu + U_WB1,
                                     ws + F_WX0E, ws + F_B0P, ws + F_B1P);
  k_init<<<128, 256, 0, stream>>>(ws + F_C0, wsu + U_H0A);

  u16* H0A = wsu + U_H0A;
  u16* H0B = wsu + U_H0B;
  u16* H1A = wsu + U_H1A;
  u16* H1B = wsu + U_H1B;

  for (int t = 0; t < SS; ++t) {
    const u16* hp = (t & 1) ? H0B : H0A;
    u16*       hn = (t & 1) ? H0A : H0B;
    k_step<1><<<dim3(64,4), 256, 0, stream>>>(wsu + U_WB0, ws + F_B0P, x,
                                              ws + F_WX0E, hp, hn,
                                              ws + F_C0, wsu + U_H1, t);
  }
  for (int t = 0; t < SS; ++t) {
    const u16* hp = (t & 1) ? H1B : H1A;
    u16*       hn = (t & 1) ? H1A : H1B;
    k_step<2><<<dim3(64,4), 256, 0, stream>>>(wsu + U_WB1, ws + F_B1P,
                                              wsu + U_H1, nullptr, hp, hn,
                                              ws + F_C1, wsu + U_H2, t);
  }
  k_proj  <<<BB*SS/8,  256, 0, stream>>>(wsu + U_H2, Wp, bp, ws + F_PROJ);
  k_scores<<<BB*SS/32, 256, 0, stream>>>(ws + F_PROJ, Wa, ba, va, ws + F_SCORE);
  k_final <<<BB,       256, 0, stream>>>(ws + F_PROJ, ws + F_SCORE, Wo, bo,
                                         (float*)d_out);
}